// Round 19
// baseline (519.043 us; speedup 1.0000x reference)
//
#include <hip/hip_runtime.h>
#include <hip/hip_bf16.h>

#define SEQ 1024
#define DIM 1024
#define NH 16

typedef __bf16 bf16_t;
typedef __bf16 bf16x8 __attribute__((ext_vector_type(8)));
typedef __bf16 bf16x4 __attribute__((ext_vector_type(4)));
typedef float f32x4 __attribute__((ext_vector_type(4)));

__device__ __forceinline__ f32x4 mfma16(bf16x8 a, bf16x8 b, f32x4 c) {
    return __builtin_amdgcn_mfma_f32_16x16x32_bf16(a, b, c, 0, 0, 0);
}

__device__ __forceinline__ void gload16(const bf16_t* g, bf16_t* l) {
    __builtin_amdgcn_global_load_lds(
        (const __attribute__((address_space(1))) void*)g,
        (__attribute__((address_space(3))) void*)l, 16, 0, 0);
}

enum { EPI_BF16 = 0, EPI_F32_RESID = 1, EPI_BF16_GELU = 2, EPI_BF16_SIGMUL = 3 };

// ---------------- fused f32 -> bf16 conversion (all weights + text) ---------
__global__ __launch_bounds__(256) void cvt_all(
    const float* __restrict__ s0, bf16_t* __restrict__ d0,
    const float* __restrict__ s1, bf16_t* __restrict__ d1,
    const float* __restrict__ s2, bf16_t* __restrict__ d2,
    const float* __restrict__ s3, bf16_t* __restrict__ d3,
    const float* __restrict__ s4, bf16_t* __restrict__ d4,
    const float* __restrict__ s5, bf16_t* __restrict__ d5,
    const float* __restrict__ s6, bf16_t* __restrict__ d6) {
    const int b = blockIdx.x;
    const float* s;
    bf16_t* d;
    int off;
    if (b < 3072) { s = s0; d = d0; off = b; }
    else if (b < 6144) { s = s1; d = d1; off = b - 3072; }
    else if (b < 7168) { s = s2; d = d2; off = b - 6144; }
    else if (b < 11264) { s = s3; d = d3; off = b - 7168; }
    else if (b < 15360) { s = s4; d = d4; off = b - 11264; }
    else if (b < 19456) { s = s5; d = d5; off = b - 15360; }
    else { s = s6; d = d6; off = b - 19456; }
    const int i = off * 256 + threadIdx.x;
    const float4 v = ((const float4*)s)[i];
    bf16x4 o = {(bf16_t)v.x, (bf16_t)v.y, (bf16_t)v.z, (bf16_t)v.w};
    ((bf16x4*)d)[i] = o;
}

// ---------------- LayerNorm: one block per row of 1024, bf16 out ------------
__global__ __launch_bounds__(256) void ln_kernel(const float* __restrict__ in,
                                                 const float* __restrict__ g,
                                                 const float* __restrict__ bsh,
                                                 bf16_t* __restrict__ out) {
    __shared__ float red[4], red2[4];
    const int row = blockIdx.x, tid = threadIdx.x;
    const float4 v = ((const float4*)(in + (size_t)row * DIM))[tid];
    float s = v.x + v.y + v.z + v.w;
#pragma unroll
    for (int o = 32; o; o >>= 1) s += __shfl_down(s, o, 64);
    if ((tid & 63) == 0) red[tid >> 6] = s;
    __syncthreads();
    const float mean = (red[0] + red[1] + red[2] + red[3]) * (1.0f / DIM);
    const float dx = v.x - mean, dy = v.y - mean, dz = v.z - mean, dw = v.w - mean;
    float s2 = dx * dx + dy * dy + dz * dz + dw * dw;
#pragma unroll
    for (int o = 32; o; o >>= 1) s2 += __shfl_xor(s2, o, 64);
    if ((tid & 63) == 0) red2[tid >> 6] = s2;
    __syncthreads();
    const float var = (red2[0] + red2[1] + red2[2] + red2[3]) * (1.0f / DIM);
    const float rs = rsqrtf(var + 1e-5f);
    const float4 gv = ((const float4*)g)[tid];
    const float4 bv = ((const float4*)bsh)[tid];
    bf16x4 o4 = {(bf16_t)(dx * rs * gv.x + bv.x), (bf16_t)(dy * rs * gv.y + bv.y),
                 (bf16_t)(dz * rs * gv.z + bv.z), (bf16_t)(dw * rs * gv.w + bv.w)};
    ((bf16x4*)(out + (size_t)row * DIM))[tid] = o4;
}

// ---------------- RoPE in-place on q,k sections of qkv (bf16) ---------------
__global__ __launch_bounds__(256) void rope_kernel(bf16_t* __restrict__ qkv,
                                                   const float* __restrict__ rp) {
    const int t = blockIdx.x * 256 + threadIdx.x;
    const int row = t >> 9;
    const int rem = t & 511;
    const int h = rem >> 5, d = rem & 31;
    const int s = row & (SEQ - 1);
    const float p0 = rp[s * 64 + d];
    const float p1 = rp[s * 64 + d + 32];
    float s0, c0, s1, c1;
    sincosf(p0, &s0, &c0);
    sincosf(p1, &s1, &c1);
    const size_t base = (size_t)row * 3072 + h * 64 + d;
#pragma unroll
    for (int off = 0; off <= 1024; off += 1024) {
        const float a = (float)qkv[base + off];
        const float b = (float)qkv[base + off + 32];
        qkv[base + off] = (bf16_t)(a * c0 - b * s0);
        qkv[base + off + 32] = (bf16_t)(b * c1 + a * s1);
    }
}

__device__ __forceinline__ float epi_apply_gelu(float v) {
    return 0.5f * v * (1.0f + erff(v * 0.70710678118f));
}

// ---------------- V^T precompute ---------------------------------------------
__global__ __launch_bounds__(256) void vtrans_kernel(
    const bf16_t* __restrict__ src, int ld, int voff, int skv,
    bf16_t* __restrict__ vt) {
    __shared__ bf16_t T[64 * 72];
    const int qt = blockIdx.x, h = blockIdx.y, b = blockIdx.z;
    const int tid = threadIdx.x;
    const int s0 = qt * 64;
#pragma unroll
    for (int t = 0; t < 2; ++t) {
        const int idx = t * 256 + tid;
        const int r = idx >> 3, c8 = (idx & 7) * 8;
        bf16x8 v = *(const bf16x8*)(src + (size_t)(b * skv + s0 + r) * ld +
                                    voff + h * 64 + c8);
        *(bf16x8*)&T[r * 72 + c8] = v;
    }
    __syncthreads();
    const size_t base = ((size_t)(b * NH + h) * 64) * skv;
#pragma unroll
    for (int t = 0; t < 2; ++t) {
        const int idx = t * 256 + tid;
        const int d = idx >> 3, s8 = (idx & 7) * 8;
        bf16x8 w;
#pragma unroll
        for (int i = 0; i < 8; ++i) w[i] = T[(s8 + i) * 72 + d];
        *(bf16x8*)(vt + base + (size_t)d * skv + s0 + s8) = w;
    }
}

// ---------------- flash attention v3: 8 waves, 128 q-rows/block -------------
#define ALD 72
template <bool OUTBF>
__global__ __launch_bounds__(512) void attn3_kernel(
    const bf16_t* __restrict__ qp, int ldq, int qoff,
    const bf16_t* __restrict__ kp, int ldk, int koff,
    const bf16_t* __restrict__ vtp, int skv,
    const float* __restrict__ resid, void* __restrict__ outp, float scale) {
    __shared__ bf16_t Ks[4096];
    __shared__ bf16_t Vs[4096];
    __shared__ bf16_t Ps[8 * 16 * ALD];
    const int nwg = gridDim.x;
    const int t = (blockIdx.x & 7) * (nwg >> 3) + (blockIdx.x >> 3);
    const int qt = t & 7;
    const int bh = t >> 3;
    const int b = bh >> 4, h = bh & 15;
    const int tid = threadIdx.x;
    const int wave = tid >> 6, lane = tid & 63;
    const int lr = lane & 15, hi = lane >> 4;

    const size_t qrow = (size_t)(b * SEQ + qt * 128 + wave * 16 + lr);
    const bf16_t* qb = qp + qrow * ldq + qoff + h * 64;
    const bf16x8 qf0 = *(const bf16x8*)(qb + hi * 8);
    const bf16x8 qf1 = *(const bf16x8*)(qb + 32 + hi * 8);

    const bf16_t* vbase = vtp + ((size_t)bh * 64) * skv;

    f32x4 oacc[4];
#pragma unroll
    for (int n = 0; n < 4; ++n) oacc[n] = (f32x4){0.f, 0.f, 0.f, 0.f};
    float mrun[4] = {-1e30f, -1e30f, -1e30f, -1e30f};
    float lrun[4] = {0.f, 0.f, 0.f, 0.f};

    bf16_t* pw = &Ps[wave * 16 * ALD];
    const int nkt = skv >> 6;
    for (int kt = 0; kt < nkt; ++kt) {
        {
            const int grow = (wave >> 1) * 16 + lr, gcol = (wave & 1) * 32 + hi * 8;
            gload16(kp + (size_t)(b * skv + kt * 64 + grow) * ldk + koff +
                        h * 64 + gcol,
                    &Ks[wave * 512]);
            gload16(vbase + (size_t)grow * skv + kt * 64 + gcol, &Vs[wave * 512]);
        }
        __syncthreads();

        f32x4 s[4];
#pragma unroll
        for (int n = 0; n < 4; ++n) {
            f32x4 z = (f32x4){0.f, 0.f, 0.f, 0.f};
            z = mfma16(qf0, *(const bf16x8*)&Ks[(n * 2 + 0) * 512 + lane * 8], z);
            z = mfma16(qf1, *(const bf16x8*)&Ks[(n * 2 + 1) * 512 + lane * 8], z);
            s[n] = z * scale;
        }
        float alpha[4];
#pragma unroll
        for (int j = 0; j < 4; ++j) {
            float mt = fmaxf(fmaxf(s[0][j], s[1][j]), fmaxf(s[2][j], s[3][j]));
#pragma unroll
            for (int o = 8; o >= 1; o >>= 1) mt = fmaxf(mt, __shfl_xor(mt, o, 64));
            const float mnew = fmaxf(mrun[j], mt);
            alpha[j] = __expf(mrun[j] - mnew);
            float rsum = 0.f;
#pragma unroll
            for (int n = 0; n < 4; ++n) {
                const float p = __expf(s[n][j] - mnew);
                s[n][j] = p;
                rsum += p;
            }
#pragma unroll
            for (int o = 8; o >= 1; o >>= 1) rsum += __shfl_xor(rsum, o, 64);
            lrun[j] = lrun[j] * alpha[j] + rsum;
            mrun[j] = mnew;
        }
#pragma unroll
        for (int j = 0; j < 4; ++j) {
            const int pr = hi * 4 + j;
#pragma unroll
            for (int n = 0; n < 4; ++n) pw[pr * ALD + n * 16 + lr] = (bf16_t)s[n][j];
        }
#pragma unroll
        for (int n = 0; n < 4; ++n)
#pragma unroll
            for (int j = 0; j < 4; ++j) oacc[n][j] *= alpha[j];
#pragma unroll
        for (int ks = 0; ks < 2; ++ks) {
            const bf16x8 pa = *(const bf16x8*)&pw[lr * ALD + ks * 32 + hi * 8];
#pragma unroll
            for (int n = 0; n < 4; ++n) {
                const bf16x8 vf =
                    *(const bf16x8*)&Vs[(n * 2 + ks) * 512 + lane * 8];
                oacc[n] = mfma16(pa, vf, oacc[n]);
            }
        }
        __syncthreads();
    }

    const size_t orow0 = (size_t)(b * SEQ + qt * 128 + wave * 16);
#pragma unroll
    for (int n = 0; n < 4; ++n) {
#pragma unroll
        for (int j = 0; j < 4; ++j) {
            const int r = hi * 4 + j;
            const size_t idx = (orow0 + r) * DIM + h * 64 + n * 16 + lr;
            float val = oacc[n][j] / lrun[j];
            if constexpr (OUTBF) {
                ((bf16_t*)outp)[idx] = (bf16_t)val;
            } else {
                ((float*)outp)[idx] = val + resid[idx];
            }
        }
    }
}

// ---------------- 128x128 bf16 GEMM, 8 waves, wave-tile 64x32, BK=64 --------
template <int EPI, int MODE>
__global__ __launch_bounds__(512, 4) void gemm8w(
    const bf16_t* __restrict__ A, int lda, const bf16_t* __restrict__ W, int ldw,
    const float* __restrict__ bias, const void* __restrict__ aux,
    void* __restrict__ outv, int ldo, int K, int nM) {
    __shared__ bf16_t As[2][8192];
    __shared__ bf16_t Bs[2][8192];
    const int tid = threadIdx.x;
    const int wave = tid >> 6, lane = tid & 63;
    const int wm = wave >> 2, wn = wave & 3;
    const int lr = lane & 15, hi = lane >> 4;

    const int x = blockIdx.x & 7, i = blockIdx.x >> 3;
    int mt, nt;
    if constexpr (MODE == 0) {
        const int mc = nM >> 3;
        mt = x * mc + (i % mc);
        nt = i / mc;
    } else {
        const int nc = (gridDim.x / nM) >> 3;
        nt = x * nc + (i % nc);
        mt = i / nc;
    }
    const int rowA0 = mt * 128, rowB0 = nt * 128;

    f32x4 acc[4][2];
#pragma unroll
    for (int m = 0; m < 4; ++m)
#pragma unroll
        for (int n = 0; n < 2; ++n) acc[m][n] = (f32x4){0.f, 0.f, 0.f, 0.f};

    auto stage = [&](int kt, int b) {
        const int k0 = kt * 64;
#pragma unroll
        for (int u = 0; u < 2; ++u) {
            const int c = wave * 2 + u;
            const int grow = wave * 16 + lr, gcol = k0 + u * 32 + hi * 8;
            gload16(A + (size_t)(rowA0 + grow) * lda + gcol, &As[b][c * 512]);
            gload16(W + (size_t)(rowB0 + grow) * ldw + gcol, &Bs[b][c * 512]);
        }
    };

    const int NT = K >> 6;
    stage(0, 0);
    stage(1, 1);
    asm volatile("s_waitcnt vmcnt(4)" ::: "memory");
    __builtin_amdgcn_s_barrier();

    for (int kt = 0; kt < NT; ++kt) {
        const int cur = kt & 1;
#pragma unroll
        for (int ks = 0; ks < 2; ++ks) {
            bf16x8 af[4], bfr[2];
#pragma unroll
            for (int mf = 0; mf < 4; ++mf)
                af[mf] = *(const bf16x8*)&As[cur][((wm * 4 + mf) * 2 + ks) * 512 +
                                                 hi * 128 + lr * 8];
#pragma unroll
            for (int nf = 0; nf < 2; ++nf)
                bfr[nf] = *(const bf16x8*)&Bs[cur][((wn * 2 + nf) * 2 + ks) * 512 +
                                                  hi * 128 + lr * 8];
#pragma unroll
            for (int mf = 0; mf < 4; ++mf)
#pragma unroll
                for (int nf = 0; nf < 2; ++nf)
                    acc[mf][nf] = mfma16(af[mf], bfr[nf], acc[mf][nf]);
        }
        if (kt + 1 < NT) {
            __builtin_amdgcn_sched_barrier(0);
            __builtin_amdgcn_s_barrier();
            if (kt + 2 < NT) {
                stage(kt + 2, cur);
                asm volatile("s_waitcnt vmcnt(4)" ::: "memory");
            } else {
                asm volatile("s_waitcnt vmcnt(0)" ::: "memory");
            }
            __builtin_amdgcn_s_barrier();
        }
    }

    float bn[2];
#pragma unroll
    for (int n = 0; n < 2; ++n) bn[n] = bias[rowB0 + wn * 32 + n * 16 + lr];
#pragma unroll
    for (int m = 0; m < 4; ++m) {
#pragma unroll
        for (int j = 0; j < 4; ++j) {
            const int row = rowA0 + wm * 64 + m * 16 + hi * 4 + j;
#pragma unroll
            for (int n = 0; n < 2; ++n) {
                const int col = rowB0 + wn * 32 + n * 16 + lr;
                float val = acc[m][n][j] + bn[n];
                const size_t oidx = (size_t)row * ldo + col;
                if constexpr (EPI == EPI_BF16) {
                    ((bf16_t*)outv)[oidx] = (bf16_t)val;
                } else {
                    ((float*)outv)[oidx] = val + ((const float*)aux)[oidx];
                }
            }
        }
    }
}

// ---------------- 256x256 bf16 GEMM, 8 waves, BK=64, 4-phase pipelined ------
// Per K-tile kt (buf cur=kt&1, nb=cur^1), wave output 128x64, quadrant order
// q(0,0) q(0,1) q(1,1) q(1,0). Region free points: B-halves after ph1,
// A-halves after ph2 (each wave reads its whole A-half across ph0+ph2).
// Stage schedule (issue after the barrier following the region's last read):
//   ph0: A1(kt+1)->nb | ph1: B0(kt+1)->nb | ph2: B1(kt+2)->cur | ph3: A0(kt+2)->cur
// Each phase: {ds_reads; stage(2 gloads); s_barrier; lgkmcnt(0)+sched_barrier;
// setprio(1); 16 MFMA; setprio(0); s_barrier}. One counted vmcnt per K-tile
// at end of ph3: 6 half-tiles outstanding, oldest 4 = tile kt+1 complete ->
// vmcnt(4) (2 half-tiles stay in flight). Epilogue tiles: vmcnt(0).
// LDS chunk layout: chunk c (16 rows x 32 cols) at elems c*512 + lane*8;
// staging linear-in-lane, fragment reads identity (conflict-free).
template <int EPI>
__global__ __launch_bounds__(512, 2) void gemm256p(
    const bf16_t* __restrict__ A, int lda, const bf16_t* __restrict__ W, int ldw,
    const float* __restrict__ bias, const void* __restrict__ aux,
    void* __restrict__ outv, int ldo, int K, int nM) {
    __shared__ bf16_t As[2][16384];
    __shared__ bf16_t Bs[2][16384];
    const int tid = threadIdx.x;
    const int wave = tid >> 6, lane = tid & 63;
    const int wm = wave >> 2, wn = wave & 3;
    const int lr = lane & 15, hi = lane >> 4;

    const int x = blockIdx.x & 7, i = blockIdx.x >> 3;
    const int mc = nM >> 3;
    const int mt = x * mc + (i % mc);
    const int nt = i / mc;
    const int rowA0 = mt * 256, rowB0 = nt * 256;

    f32x4 acc[8][4];
#pragma unroll
    for (int m = 0; m < 8; ++m)
#pragma unroll
        for (int n = 0; n < 4; ++n) acc[m][n] = (f32x4){0.f, 0.f, 0.f, 0.f};

    // stage one half (16 chunks) of A or B for K-tile kt into buffer b
    auto stA = [&](int kt, int b, int h) {
#pragma unroll
        for (int u = 0; u < 2; ++u) {
            const int c = h * 16 + wave * 2 + u;
            const int grow = rowA0 + (c >> 1) * 16 + lr;
            const int gcol = kt * 64 + (c & 1) * 32 + hi * 8;
            gload16(A + (size_t)grow * lda + gcol, &As[b][c * 512]);
        }
    };
    auto stB = [&](int kt, int b, int h) {
#pragma unroll
        for (int u = 0; u < 2; ++u) {
            const int c = h * 16 + wave * 2 + u;
            const int grow = rowB0 + (c >> 1) * 16 + lr;
            const int gcol = kt * 64 + (c & 1) * 32 + hi * 8;
            gload16(W + (size_t)grow * ldw + gcol, &Bs[b][c * 512]);
        }
    };

    const int NT = K >> 6;
    // prologue: tile0 all 4 halves, then B1(t1), A0(t1)
    stA(0, 0, 0);
    stA(0, 0, 1);
    stB(0, 0, 0);
    stB(0, 0, 1);
    if (1 < NT) {
        stB(1, 1, 1);
        stA(1, 1, 0);
    }
    asm volatile("s_waitcnt vmcnt(4)" ::: "memory");
    __builtin_amdgcn_s_barrier();

    for (int kt = 0; kt < NT; ++kt) {
        const int cur = kt & 1, nb = cur ^ 1;
        const bool k1 = (kt + 1 < NT), k2 = (kt + 2 < NT);
        bf16x8 af[4], b0[2][2], b1[2][2];

        // ---- ph0: q(0,0) — reads af[0..3](x2 ks folded below), b0 ----
        bf16x8 af0[4][2];
#pragma unroll
        for (int mf = 0; mf < 4; ++mf)
#pragma unroll
            for (int ks = 0; ks < 2; ++ks)
                af0[mf][ks] = *(const bf16x8*)&As[cur][((wm * 8 + mf) * 2 + ks) * 512 +
                                                      lane * 8];
#pragma unroll
        for (int nf = 0; nf < 2; ++nf)
#pragma unroll
            for (int ks = 0; ks < 2; ++ks)
                b0[nf][ks] = *(const bf16x8*)&Bs[cur][((wn * 4 + nf) * 2 + ks) * 512 +
                                                     lane * 8];
        if (k1) stA(kt + 1, nb, 1);
        __builtin_amdgcn_s_barrier();
        asm volatile("s_waitcnt lgkmcnt(0)" ::: "memory");
        __builtin_amdgcn_sched_barrier(0);
        __builtin_amdgcn_s_setprio(1);
#pragma unroll
        for (int mf = 0; mf < 4; ++mf)
#pragma unroll
            for (int nf = 0; nf < 2; ++nf)
#pragma unroll
                for (int ks = 0; ks < 2; ++ks)
                    acc[mf][nf] = mfma16(af0[mf][ks], b0[nf][ks], acc[mf][nf]);
        __builtin_amdgcn_s_setprio(0);
        __builtin_amdgcn_s_barrier();

        // ---- ph1: q(0,1) — reads b1 ----
#pragma unroll
        for (int nf = 0; nf < 2; ++nf)
#pragma unroll
            for (int ks = 0; ks < 2; ++ks)
                b1[nf][ks] = *(const bf16x8*)&Bs[cur][((wn * 4 + 2 + nf) * 2 + ks) * 512 +
                                                     lane * 8];
        if (k1) stB(kt + 1, nb, 0);
        __builtin_amdgcn_s_barrier();
        asm volatile("s_waitcnt lgkmcnt(0)" ::: "memory");
        __builtin_amdgcn_sched_barrier(0);
        __builtin_amdgcn_s_setprio(1);
#pragma unroll
        for (int mf = 0; mf < 4; ++mf)
#pragma unroll
            for (int nf = 0; nf < 2; ++nf)
#pragma unroll
                for (int ks = 0; ks < 2; ++ks)
                    acc[mf][nf + 2] = mfma16(af0[mf][ks], b1[nf][ks], acc[mf][nf + 2]);
        __builtin_amdgcn_s_setprio(0);
        __builtin_amdgcn_s_barrier();

        // ---- ph2: q(1,1) — reads af[4..7] ----
        bf16x8 af1[4][2];
#pragma unroll
        for (int mf = 0; mf < 4; ++mf)
#pragma unroll
            for (int ks = 0; ks < 2; ++ks)
                af1[mf][ks] = *(const bf16x8*)&As[cur][((wm * 8 + 4 + mf) * 2 + ks) * 512 +
                                                      lane * 8];
        if (k2) stB(kt + 2, cur, 1);
        __builtin_amdgcn_s_barrier();
        asm volatile("s_waitcnt lgkmcnt(0)" ::: "memory");
        __builtin_amdgcn_sched_barrier(0);
        __builtin_amdgcn_s_setprio(1);
#pragma unroll
        for (int mf = 0; mf < 4; ++mf)
#pragma unroll
            for (int nf = 0; nf < 2; ++nf)
#pragma unroll
                for (int ks = 0; ks < 2; ++ks)
                    acc[mf + 4][nf + 2] = mfma16(af1[mf][ks], b1[nf][ks], acc[mf + 4][nf + 2]);
        __builtin_amdgcn_s_setprio(0);
        __builtin_amdgcn_s_barrier();

        // ---- ph3: q(1,0) — no new ds_reads ----
        if (k2) stA(kt + 2, cur, 0);
        __builtin_amdgcn_s_barrier();
        __builtin_amdgcn_s_setprio(1);
#pragma unroll
        for (int mf = 0; mf < 4; ++mf)
#pragma unroll
            for (int nf = 0; nf < 2; ++nf)
#pragma unroll
                for (int ks = 0; ks < 2; ++ks)
                    acc[mf + 4][nf] = mfma16(af1[mf][ks], b0[nf][ks], acc[mf + 4][nf]);
        __builtin_amdgcn_s_setprio(0);
        if (k1) {
            if (k2)
                asm volatile("s_waitcnt vmcnt(4)" ::: "memory");
            else
                asm volatile("s_waitcnt vmcnt(0)" ::: "memory");
            __builtin_amdgcn_s_barrier();
        }
        (void)af[0];
    }

    float bn[4];
#pragma unroll
    for (int n = 0; n < 4; ++n) bn[n] = bias[rowB0 + wn * 64 + n * 16 + lr];
#pragma unroll
    for (int m = 0; m < 8; ++m) {
#pragma unroll
        for (int j = 0; j < 4; ++j) {
            const int row = rowA0 + wm * 128 + m * 16 + hi * 4 + j;
#pragma unroll
            for (int n = 0; n < 4; ++n) {
                const int col = rowB0 + wn * 64 + n * 16 + lr;
                float val = acc[m][n][j] + bn[n];
                const size_t oidx = (size_t)row * ldo + col;
                if constexpr (EPI == EPI_BF16_GELU) {
                    ((bf16_t*)outv)[oidx] = (bf16_t)epi_apply_gelu(val);
                } else if constexpr (EPI == EPI_BF16_SIGMUL) {
                    const float sg = 1.0f / (1.0f + __expf(-val));
                    ((bf16_t*)outv)[oidx] =
                        (bf16_t)(sg * (float)((const bf16_t*)aux)[oidx]);
                } else {
                    ((bf16_t*)outv)[oidx] = (bf16_t)val;
                }
            }
        }
    }
}

// ---------------- split-K fc2 GEMM: 128x128 tile, 2 K-splits ----------------
__global__ __launch_bounds__(512, 4) void gemm8w_sk(
    const bf16_t* __restrict__ A, int lda, const bf16_t* __restrict__ W, int ldw,
    float* __restrict__ p0, float* __restrict__ p1, int ldo, int Khalf, int nM) {
    __shared__ bf16_t As[2][8192];
    __shared__ bf16_t Bs[2][8192];
    const int tid = threadIdx.x;
    const int wave = tid >> 6, lane = tid & 63;
    const int wm = wave >> 2, wn = wave & 3;
    const int lr = lane & 15, hi = lane >> 4;

    const int sk = blockIdx.x >> 8;
    const int bi = blockIdx.x & 255;
    const int x = bi & 7, i = bi >> 3;
    const int mc = nM >> 3;
    const int mt = x * mc + (i % mc);
    const int nt = i / mc;
    const int rowA0 = mt * 128, rowB0 = nt * 128;
    const int kbase = sk * Khalf;
    float* outp = sk ? p1 : p0;

    f32x4 acc[4][2];
#pragma unroll
    for (int m = 0; m < 4; ++m)
#pragma unroll
        for (int n = 0; n < 2; ++n) acc[m][n] = (f32x4){0.f, 0.f, 0.f, 0.f};

    auto stage = [&](int kt, int b) {
        const int k0 = kbase + kt * 64;
#pragma unroll
        for (int u = 0; u < 2; ++u) {
            const int c = wave * 2 + u;
            const int grow = wave * 16 + lr, gcol = k0 + u * 32 + hi * 8;
            gload16(A + (size_t)(rowA0 + grow) * lda + gcol, &As[b][c * 512]);
            gload16(W + (size_t)(rowB0 + grow) * ldw + gcol, &Bs[b][c * 512]);
        }
    };

    const int NT = Khalf >> 6;
    stage(0, 0);
    stage(1, 1);
    asm volatile("s_waitcnt vmcnt(4)" ::: "memory");
    __builtin_amdgcn_s_barrier();

    for (int kt = 0; kt < NT; ++kt) {
        const int cur = kt & 1;
#pragma unroll
        for (int ks = 0; ks < 2; ++ks) {
            bf16x8 af[4], bfr[2];
#pragma unroll
            for (int mf = 0; mf < 4; ++mf)
                af[mf] = *(const bf16x8*)&As[cur][((wm * 4 + mf) * 2 + ks) * 512 +
                                                 hi * 128 + lr * 8];
#pragma unroll
            for (int nf = 0; nf < 2; ++nf)
                bfr[nf] = *(const bf16x8*)&Bs[cur][((wn * 2 + nf) * 2 + ks) * 512 +
                                                  hi * 128 + lr * 8];
#pragma unroll
            for (int mf = 0; mf < 4; ++mf)
#pragma unroll
                for (int nf = 0; nf < 2; ++nf)
                    acc[mf][nf] = mfma16(af[mf], bfr[nf], acc[mf][nf]);
        }
        if (kt + 1 < NT) {
            __builtin_amdgcn_sched_barrier(0);
            __builtin_amdgcn_s_barrier();
            if (kt + 2 < NT) {
                stage(kt + 2, cur);
                asm volatile("s_waitcnt vmcnt(4)" ::: "memory");
            } else {
                asm volatile("s_waitcnt vmcnt(0)" ::: "memory");
            }
            __builtin_amdgcn_s_barrier();
        }
    }

#pragma unroll
    for (int m = 0; m < 4; ++m) {
#pragma unroll
        for (int j = 0; j < 4; ++j) {
            const int row = rowA0 + wm * 64 + m * 16 + hi * 4 + j;
#pragma unroll
            for (int n = 0; n < 2; ++n) {
                const int col = rowB0 + wn * 32 + n * 16 + lr;
                outp[(size_t)row * ldo + col] = acc[m][n][j];
            }
        }
    }
}

// out = p0(out) + p1 + bias + resid
__global__ __launch_bounds__(256) void reduce_fc2(
    float* __restrict__ outp, const float* __restrict__ p1,
    const float* __restrict__ bias, const float* __restrict__ resid) {
    const int i = blockIdx.x * 256 + threadIdx.x;
    const float4 a = ((const float4*)outp)[i];
    const float4 b = ((const float4*)p1)[i];
    const float4 r = ((const float4*)resid)[i];
    const float4 bv = ((const float4*)bias)[i & 255];
    float4 o;
    o.x = a.x + b.x + r.x + bv.x;
    o.y = a.y + b.y + r.y + bv.y;
    o.z = a.z + b.z + r.z + bv.z;
    o.w = a.w + b.w + r.w + bv.w;
    ((float4*)outp)[i] = o;
}

extern "C" void kernel_launch(void* const* d_in, const int* in_sizes, int n_in,
                              void* d_out, int out_size, void* d_ws, size_t ws_size,
                              hipStream_t stream) {
    const float* x = (const float*)d_in[0];
    const float* text_emb = (const float*)d_in[1];
    const float* rotary = (const float*)d_in[3];
    const float* ln1_g = (const float*)d_in[4];
    const float* ln1_b = (const float*)d_in[5];
    const float* ln2_g = (const float*)d_in[6];
    const float* ln2_b = (const float*)d_in[7];
    const float* ln3_g = (const float*)d_in[8];
    const float* ln3_b = (const float*)d_in[9];
    const float* attn_in_w = (const float*)d_in[10];
    const float* attn_in_b = (const float*)d_in[11];
    const float* ca_in_w = (const float*)d_in[12];
    const float* ca_in_b = (const float*)d_in[13];
    const float* ca_out_w = (const float*)d_in[14];
    const float* ca_out_b = (const float*)d_in[15];
    const float* fc1_w = (const float*)d_in[16];
    const float* fc1_b = (const float*)d_in[17];
    const float* gate_w = (const float*)d_in[18];
    const float* gate_b = (const float*)d_in[19];
    const float* fc2_w = (const float*)d_in[20];
    const float* fc2_b = (const float*)d_in[21];

    char* ws = (char*)d_ws;
    bf16_t* attn_w_bf = (bf16_t*)(ws);
    bf16_t* ca_in_bf = (bf16_t*)(ws + 6291456);
    bf16_t* ca_out_bf = (bf16_t*)(ws + 12582912);
    bf16_t* fc1_bf = (bf16_t*)(ws + 14680064);
    bf16_t* gate_bf = (bf16_t*)(ws + 23068672);
    bf16_t* fc2_bf = (bf16_t*)(ws + 31457280);
    bf16_t* text_bf = (bf16_t*)(ws + 39845888);
    bf16_t* xn = (bf16_t*)(ws + 41943040);
    float* xA = (float*)(ws + 50331648);
    float* fc2_p1 = (float*)(ws + 14680064);
    char* S = ws + 67108864;
    bf16_t* qkv = (bf16_t*)S;
    bf16_t* vtSelf = (bf16_t*)(S + 25165824);
    bf16_t* cq = (bf16_t*)S;
    bf16_t* ckv = (bf16_t*)(S + 8388608);
    bf16_t* ca_attn = (bf16_t*)(S + 12582912);
    bf16_t* vtCross = (bf16_t*)(S + 20971520);
    bf16_t* hbuf = (bf16_t*)S;
    float* out = (float*)d_out;

    cvt_all<<<20480, 256, 0, stream>>>(attn_in_w, attn_w_bf, ca_in_w, ca_in_bf,
                                       ca_out_w, ca_out_bf, fc1_w, fc1_bf,
                                       gate_w, gate_bf, fc2_w, fc2_bf,
                                       text_emb, text_bf);

    // ---- self-attention branch ----
    ln_kernel<<<4096, 256, 0, stream>>>(x, ln1_g, ln1_b, xn);
    gemm8w<EPI_BF16, 0><<<768, 512, 0, stream>>>(
        xn, 1024, attn_w_bf, 1024, attn_in_b, nullptr, qkv, 3072, 1024, 32);
    rope_kernel<<<8192, 256, 0, stream>>>(qkv, rotary);
    vtrans_kernel<<<dim3(16, 16, 4), 256, 0, stream>>>(qkv, 3072, 2048, 1024, vtSelf);
    attn3_kernel<false><<<512, 512, 0, stream>>>(
        qkv, 3072, 0, qkv, 3072, 1024, vtSelf, 1024, x, xA, 0.125f);

    // ---- cross-attention branch ----
    ln_kernel<<<4096, 256, 0, stream>>>(xA, ln2_g, ln2_b, xn);
    gemm8w<EPI_BF16, 0><<<256, 512, 0, stream>>>(
        xn, 1024, ca_in_bf, 1024, ca_in_b, nullptr, cq, 1024, 1024, 32);
    gemm8w<EPI_BF16, 1><<<128, 512, 0, stream>>>(
        text_bf, 1024, ca_in_bf + (size_t)1024 * 1024, 1024, ca_in_b + 1024, nullptr,
        ckv, 2048, 1024, 8);
    vtrans_kernel<<<dim3(4, 16, 4), 256, 0, stream>>>(ckv, 2048, 1024, 256, vtCross);
    attn3_kernel<true><<<512, 512, 0, stream>>>(
        cq, 1024, 0, ckv, 2048, 0, vtCross, 256, nullptr, ca_attn, 0.125f);
    gemm8w<EPI_F32_RESID, 0><<<256, 512, 0, stream>>>(
        ca_attn, 1024, ca_out_bf, 1024, ca_out_b, xA, xA, 1024, 1024, 32);

    // ---- MLP branch ----
    ln_kernel<<<4096, 256, 0, stream>>>(xA, ln3_g, ln3_b, xn);
    gemm256p<EPI_BF16_GELU><<<256, 512, 0, stream>>>(
        xn, 1024, fc1_bf, 1024, fc1_b, nullptr, hbuf, 4096, 1024, 16);
    gemm256p<EPI_BF16_SIGMUL><<<256, 512, 0, stream>>>(
        xn, 1024, gate_bf, 1024, gate_b, hbuf, hbuf, 4096, 1024, 16);
    gemm8w_sk<<<512, 512, 0, stream>>>(
        hbuf, 4096, fc2_bf, 4096, out, fc2_p1, 1024, 2048, 32);
    reduce_fc2<<<4096, 256, 0, stream>>>(out, fc2_p1, fc2_b, xA);
}

// Round 20
// 477.647 us; speedup vs baseline: 1.0867x; 1.0867x over previous
//
#include <hip/hip_runtime.h>
#include <hip/hip_bf16.h>

#define SEQ 1024
#define DIM 1024
#define NH 16

typedef __bf16 bf16_t;
typedef __bf16 bf16x8 __attribute__((ext_vector_type(8)));
typedef __bf16 bf16x4 __attribute__((ext_vector_type(4)));
typedef float f32x4 __attribute__((ext_vector_type(4)));

__device__ __forceinline__ f32x4 mfma16(bf16x8 a, bf16x8 b, f32x4 c) {
    return __builtin_amdgcn_mfma_f32_16x16x32_bf16(a, b, c, 0, 0, 0);
}

__device__ __forceinline__ void gload16(const bf16_t* g, bf16_t* l) {
    __builtin_amdgcn_global_load_lds(
        (const __attribute__((address_space(1))) void*)g,
        (__attribute__((address_space(3))) void*)l, 16, 0, 0);
}

enum { EPI_BF16 = 0, EPI_F32_RESID = 1 };

// ---------------- fused f32 -> bf16 conversion (all weights + text) ---------
__global__ __launch_bounds__(256) void cvt_all(
    const float* __restrict__ s0, bf16_t* __restrict__ d0,
    const float* __restrict__ s1, bf16_t* __restrict__ d1,
    const float* __restrict__ s2, bf16_t* __restrict__ d2,
    const float* __restrict__ s3, bf16_t* __restrict__ d3,
    const float* __restrict__ s4, bf16_t* __restrict__ d4,
    const float* __restrict__ s5, bf16_t* __restrict__ d5,
    const float* __restrict__ s6, bf16_t* __restrict__ d6) {
    const int b = blockIdx.x;
    const float* s;
    bf16_t* d;
    int off;
    if (b < 3072) { s = s0; d = d0; off = b; }
    else if (b < 6144) { s = s1; d = d1; off = b - 3072; }
    else if (b < 7168) { s = s2; d = d2; off = b - 6144; }
    else if (b < 11264) { s = s3; d = d3; off = b - 7168; }
    else if (b < 15360) { s = s4; d = d4; off = b - 11264; }
    else if (b < 19456) { s = s5; d = d5; off = b - 15360; }
    else { s = s6; d = d6; off = b - 19456; }
    const int i = off * 256 + threadIdx.x;
    const float4 v = ((const float4*)s)[i];
    bf16x4 o = {(bf16_t)v.x, (bf16_t)v.y, (bf16_t)v.z, (bf16_t)v.w};
    ((bf16x4*)d)[i] = o;
}

// ---------------- LayerNorm: one block per row of 1024, bf16 out ------------
__global__ __launch_bounds__(256) void ln_kernel(const float* __restrict__ in,
                                                 const float* __restrict__ g,
                                                 const float* __restrict__ bsh,
                                                 bf16_t* __restrict__ out) {
    __shared__ float red[4], red2[4];
    const int row = blockIdx.x, tid = threadIdx.x;
    const float4 v = ((const float4*)(in + (size_t)row * DIM))[tid];
    float s = v.x + v.y + v.z + v.w;
#pragma unroll
    for (int o = 32; o; o >>= 1) s += __shfl_down(s, o, 64);
    if ((tid & 63) == 0) red[tid >> 6] = s;
    __syncthreads();
    const float mean = (red[0] + red[1] + red[2] + red[3]) * (1.0f / DIM);
    const float dx = v.x - mean, dy = v.y - mean, dz = v.z - mean, dw = v.w - mean;
    float s2 = dx * dx + dy * dy + dz * dz + dw * dw;
#pragma unroll
    for (int o = 32; o; o >>= 1) s2 += __shfl_xor(s2, o, 64);
    if ((tid & 63) == 0) red2[tid >> 6] = s2;
    __syncthreads();
    const float var = (red2[0] + red2[1] + red2[2] + red2[3]) * (1.0f / DIM);
    const float rs = rsqrtf(var + 1e-5f);
    const float4 gv = ((const float4*)g)[tid];
    const float4 bv = ((const float4*)bsh)[tid];
    bf16x4 o4 = {(bf16_t)(dx * rs * gv.x + bv.x), (bf16_t)(dy * rs * gv.y + bv.y),
                 (bf16_t)(dz * rs * gv.z + bv.z), (bf16_t)(dw * rs * gv.w + bv.w)};
    ((bf16x4*)(out + (size_t)row * DIM))[tid] = o4;
}

// ---------------- RoPE in-place on q,k sections of qkv (bf16) ---------------
__global__ __launch_bounds__(256) void rope_kernel(bf16_t* __restrict__ qkv,
                                                   const float* __restrict__ rp) {
    const int t = blockIdx.x * 256 + threadIdx.x;
    const int row = t >> 9;
    const int rem = t & 511;
    const int h = rem >> 5, d = rem & 31;
    const int s = row & (SEQ - 1);
    const float p0 = rp[s * 64 + d];
    const float p1 = rp[s * 64 + d + 32];
    float s0, c0, s1, c1;
    sincosf(p0, &s0, &c0);
    sincosf(p1, &s1, &c1);
    const size_t base = (size_t)row * 3072 + h * 64 + d;
#pragma unroll
    for (int off = 0; off <= 1024; off += 1024) {
        const float a = (float)qkv[base + off];
        const float b = (float)qkv[base + off + 32];
        qkv[base + off] = (bf16_t)(a * c0 - b * s0);
        qkv[base + off + 32] = (bf16_t)(b * c1 + a * s1);
    }
}

__device__ __forceinline__ float epi_apply_gelu(float v) {
    return 0.5f * v * (1.0f + erff(v * 0.70710678118f));
}

// ---------------- V^T precompute ---------------------------------------------
__global__ __launch_bounds__(256) void vtrans_kernel(
    const bf16_t* __restrict__ src, int ld, int voff, int skv,
    bf16_t* __restrict__ vt) {
    __shared__ bf16_t T[64 * 72];
    const int qt = blockIdx.x, h = blockIdx.y, b = blockIdx.z;
    const int tid = threadIdx.x;
    const int s0 = qt * 64;
#pragma unroll
    for (int t = 0; t < 2; ++t) {
        const int idx = t * 256 + tid;
        const int r = idx >> 3, c8 = (idx & 7) * 8;
        bf16x8 v = *(const bf16x8*)(src + (size_t)(b * skv + s0 + r) * ld +
                                    voff + h * 64 + c8);
        *(bf16x8*)&T[r * 72 + c8] = v;
    }
    __syncthreads();
    const size_t base = ((size_t)(b * NH + h) * 64) * skv;
#pragma unroll
    for (int t = 0; t < 2; ++t) {
        const int idx = t * 256 + tid;
        const int d = idx >> 3, s8 = (idx & 7) * 8;
        bf16x8 w;
#pragma unroll
        for (int i = 0; i < 8; ++i) w[i] = T[(s8 + i) * 72 + d];
        *(bf16x8*)(vt + base + (size_t)d * skv + s0 + s8) = w;
    }
}

// ---------------- flash attention v3: 8 waves, 128 q-rows/block -------------
#define ALD 72
template <bool OUTBF>
__global__ __launch_bounds__(512) void attn3_kernel(
    const bf16_t* __restrict__ qp, int ldq, int qoff,
    const bf16_t* __restrict__ kp, int ldk, int koff,
    const bf16_t* __restrict__ vtp, int skv,
    const float* __restrict__ resid, void* __restrict__ outp, float scale) {
    __shared__ bf16_t Ks[4096];
    __shared__ bf16_t Vs[4096];
    __shared__ bf16_t Ps[8 * 16 * ALD];
    const int nwg = gridDim.x;
    const int t = (blockIdx.x & 7) * (nwg >> 3) + (blockIdx.x >> 3);
    const int qt = t & 7;
    const int bh = t >> 3;
    const int b = bh >> 4, h = bh & 15;
    const int tid = threadIdx.x;
    const int wave = tid >> 6, lane = tid & 63;
    const int lr = lane & 15, hi = lane >> 4;

    const size_t qrow = (size_t)(b * SEQ + qt * 128 + wave * 16 + lr);
    const bf16_t* qb = qp + qrow * ldq + qoff + h * 64;
    const bf16x8 qf0 = *(const bf16x8*)(qb + hi * 8);
    const bf16x8 qf1 = *(const bf16x8*)(qb + 32 + hi * 8);

    const bf16_t* vbase = vtp + ((size_t)bh * 64) * skv;

    f32x4 oacc[4];
#pragma unroll
    for (int n = 0; n < 4; ++n) oacc[n] = (f32x4){0.f, 0.f, 0.f, 0.f};
    float mrun[4] = {-1e30f, -1e30f, -1e30f, -1e30f};
    float lrun[4] = {0.f, 0.f, 0.f, 0.f};

    bf16_t* pw = &Ps[wave * 16 * ALD];
    const int nkt = skv >> 6;
    for (int kt = 0; kt < nkt; ++kt) {
        {
            const int grow = (wave >> 1) * 16 + lr, gcol = (wave & 1) * 32 + hi * 8;
            gload16(kp + (size_t)(b * skv + kt * 64 + grow) * ldk + koff +
                        h * 64 + gcol,
                    &Ks[wave * 512]);
            gload16(vbase + (size_t)grow * skv + kt * 64 + gcol, &Vs[wave * 512]);
        }
        __syncthreads();

        f32x4 s[4];
#pragma unroll
        for (int n = 0; n < 4; ++n) {
            f32x4 z = (f32x4){0.f, 0.f, 0.f, 0.f};
            z = mfma16(qf0, *(const bf16x8*)&Ks[(n * 2 + 0) * 512 + lane * 8], z);
            z = mfma16(qf1, *(const bf16x8*)&Ks[(n * 2 + 1) * 512 + lane * 8], z);
            s[n] = z * scale;
        }
        float alpha[4];
#pragma unroll
        for (int j = 0; j < 4; ++j) {
            float mt = fmaxf(fmaxf(s[0][j], s[1][j]), fmaxf(s[2][j], s[3][j]));
#pragma unroll
            for (int o = 8; o >= 1; o >>= 1) mt = fmaxf(mt, __shfl_xor(mt, o, 64));
            const float mnew = fmaxf(mrun[j], mt);
            alpha[j] = __expf(mrun[j] - mnew);
            float rsum = 0.f;
#pragma unroll
            for (int n = 0; n < 4; ++n) {
                const float p = __expf(s[n][j] - mnew);
                s[n][j] = p;
                rsum += p;
            }
#pragma unroll
            for (int o = 8; o >= 1; o >>= 1) rsum += __shfl_xor(rsum, o, 64);
            lrun[j] = lrun[j] * alpha[j] + rsum;
            mrun[j] = mnew;
        }
#pragma unroll
        for (int j = 0; j < 4; ++j) {
            const int pr = hi * 4 + j;
#pragma unroll
            for (int n = 0; n < 4; ++n) pw[pr * ALD + n * 16 + lr] = (bf16_t)s[n][j];
        }
#pragma unroll
        for (int n = 0; n < 4; ++n)
#pragma unroll
            for (int j = 0; j < 4; ++j) oacc[n][j] *= alpha[j];
#pragma unroll
        for (int ks = 0; ks < 2; ++ks) {
            const bf16x8 pa = *(const bf16x8*)&pw[lr * ALD + ks * 32 + hi * 8];
#pragma unroll
            for (int n = 0; n < 4; ++n) {
                const bf16x8 vf =
                    *(const bf16x8*)&Vs[(n * 2 + ks) * 512 + lane * 8];
                oacc[n] = mfma16(pa, vf, oacc[n]);
            }
        }
        __syncthreads();
    }

    const size_t orow0 = (size_t)(b * SEQ + qt * 128 + wave * 16);
#pragma unroll
    for (int n = 0; n < 4; ++n) {
#pragma unroll
        for (int j = 0; j < 4; ++j) {
            const int r = hi * 4 + j;
            const size_t idx = (orow0 + r) * DIM + h * 64 + n * 16 + lr;
            float val = oacc[n][j] / lrun[j];
            if constexpr (OUTBF) {
                ((bf16_t*)outp)[idx] = (bf16_t)val;
            } else {
                ((float*)outp)[idx] = val + resid[idx];
            }
        }
    }
}

// ---------------- 128x128 bf16 GEMM, 8 waves, wave-tile 64x32, BK=64 --------
template <int EPI, int MODE>
__global__ __launch_bounds__(512, 4) void gemm8w(
    const bf16_t* __restrict__ A, int lda, const bf16_t* __restrict__ W, int ldw,
    const float* __restrict__ bias, const void* __restrict__ aux,
    void* __restrict__ outv, int ldo, int K, int nM) {
    __shared__ bf16_t As[2][8192];
    __shared__ bf16_t Bs[2][8192];
    const int tid = threadIdx.x;
    const int wave = tid >> 6, lane = tid & 63;
    const int wm = wave >> 2, wn = wave & 3;
    const int lr = lane & 15, hi = lane >> 4;

    const int x = blockIdx.x & 7, i = blockIdx.x >> 3;
    int mt, nt;
    if constexpr (MODE == 0) {
        const int mc = nM >> 3;
        mt = x * mc + (i % mc);
        nt = i / mc;
    } else {
        const int nc = (gridDim.x / nM) >> 3;
        nt = x * nc + (i % nc);
        mt = i / nc;
    }
    const int rowA0 = mt * 128, rowB0 = nt * 128;

    f32x4 acc[4][2];
#pragma unroll
    for (int m = 0; m < 4; ++m)
#pragma unroll
        for (int n = 0; n < 2; ++n) acc[m][n] = (f32x4){0.f, 0.f, 0.f, 0.f};

    auto stage = [&](int kt, int b) {
        const int k0 = kt * 64;
#pragma unroll
        for (int u = 0; u < 2; ++u) {
            const int c = wave * 2 + u;
            const int grow = wave * 16 + lr, gcol = k0 + u * 32 + hi * 8;
            gload16(A + (size_t)(rowA0 + grow) * lda + gcol, &As[b][c * 512]);
            gload16(W + (size_t)(rowB0 + grow) * ldw + gcol, &Bs[b][c * 512]);
        }
    };

    const int NT = K >> 6;
    stage(0, 0);
    stage(1, 1);
    asm volatile("s_waitcnt vmcnt(4)" ::: "memory");
    __builtin_amdgcn_s_barrier();

    for (int kt = 0; kt < NT; ++kt) {
        const int cur = kt & 1;
#pragma unroll
        for (int ks = 0; ks < 2; ++ks) {
            bf16x8 af[4], bfr[2];
#pragma unroll
            for (int mf = 0; mf < 4; ++mf)
                af[mf] = *(const bf16x8*)&As[cur][((wm * 4 + mf) * 2 + ks) * 512 +
                                                 hi * 128 + lr * 8];
#pragma unroll
            for (int nf = 0; nf < 2; ++nf)
                bfr[nf] = *(const bf16x8*)&Bs[cur][((wn * 2 + nf) * 2 + ks) * 512 +
                                                  hi * 128 + lr * 8];
#pragma unroll
            for (int mf = 0; mf < 4; ++mf)
#pragma unroll
                for (int nf = 0; nf < 2; ++nf)
                    acc[mf][nf] = mfma16(af[mf], bfr[nf], acc[mf][nf]);
        }
        if (kt + 1 < NT) {
            __builtin_amdgcn_sched_barrier(0);
            __builtin_amdgcn_s_barrier();
            if (kt + 2 < NT) {
                stage(kt + 2, cur);
                asm volatile("s_waitcnt vmcnt(4)" ::: "memory");
            } else {
                asm volatile("s_waitcnt vmcnt(0)" ::: "memory");
            }
            __builtin_amdgcn_s_barrier();
        }
    }

    float bn[2];
#pragma unroll
    for (int n = 0; n < 2; ++n) bn[n] = bias[rowB0 + wn * 32 + n * 16 + lr];
#pragma unroll
    for (int m = 0; m < 4; ++m) {
#pragma unroll
        for (int j = 0; j < 4; ++j) {
            const int row = rowA0 + wm * 64 + m * 16 + hi * 4 + j;
#pragma unroll
            for (int n = 0; n < 2; ++n) {
                const int col = rowB0 + wn * 32 + n * 16 + lr;
                float val = acc[m][n][j] + bn[n];
                const size_t oidx = (size_t)row * ldo + col;
                if constexpr (EPI == EPI_BF16) {
                    ((bf16_t*)outv)[oidx] = (bf16_t)val;
                } else {
                    ((float*)outv)[oidx] = val + ((const float*)aux)[oidx];
                }
            }
        }
    }
}

// ---------------- split-K fc2 GEMM: 128x128 tile, 2 K-splits ----------------
__global__ __launch_bounds__(512, 4) void gemm8w_sk(
    const bf16_t* __restrict__ A, int lda, const bf16_t* __restrict__ W, int ldw,
    float* __restrict__ p0, float* __restrict__ p1, int ldo, int Khalf, int nM) {
    __shared__ bf16_t As[2][8192];
    __shared__ bf16_t Bs[2][8192];
    const int tid = threadIdx.x;
    const int wave = tid >> 6, lane = tid & 63;
    const int wm = wave >> 2, wn = wave & 3;
    const int lr = lane & 15, hi = lane >> 4;

    const int sk = blockIdx.x >> 8;
    const int bi = blockIdx.x & 255;
    const int x = bi & 7, i = bi >> 3;
    const int mc = nM >> 3;
    const int mt = x * mc + (i % mc);
    const int nt = i / mc;
    const int rowA0 = mt * 128, rowB0 = nt * 128;
    const int kbase = sk * Khalf;
    float* outp = sk ? p1 : p0;

    f32x4 acc[4][2];
#pragma unroll
    for (int m = 0; m < 4; ++m)
#pragma unroll
        for (int n = 0; n < 2; ++n) acc[m][n] = (f32x4){0.f, 0.f, 0.f, 0.f};

    auto stage = [&](int kt, int b) {
        const int k0 = kbase + kt * 64;
#pragma unroll
        for (int u = 0; u < 2; ++u) {
            const int c = wave * 2 + u;
            const int grow = wave * 16 + lr, gcol = k0 + u * 32 + hi * 8;
            gload16(A + (size_t)(rowA0 + grow) * lda + gcol, &As[b][c * 512]);
            gload16(W + (size_t)(rowB0 + grow) * ldw + gcol, &Bs[b][c * 512]);
        }
    };

    const int NT = Khalf >> 6;
    stage(0, 0);
    stage(1, 1);
    asm volatile("s_waitcnt vmcnt(4)" ::: "memory");
    __builtin_amdgcn_s_barrier();

    for (int kt = 0; kt < NT; ++kt) {
        const int cur = kt & 1;
#pragma unroll
        for (int ks = 0; ks < 2; ++ks) {
            bf16x8 af[4], bfr[2];
#pragma unroll
            for (int mf = 0; mf < 4; ++mf)
                af[mf] = *(const bf16x8*)&As[cur][((wm * 4 + mf) * 2 + ks) * 512 +
                                                 hi * 128 + lr * 8];
#pragma unroll
            for (int nf = 0; nf < 2; ++nf)
                bfr[nf] = *(const bf16x8*)&Bs[cur][((wn * 2 + nf) * 2 + ks) * 512 +
                                                  hi * 128 + lr * 8];
#pragma unroll
            for (int mf = 0; mf < 4; ++mf)
#pragma unroll
                for (int nf = 0; nf < 2; ++nf)
                    acc[mf][nf] = mfma16(af[mf], bfr[nf], acc[mf][nf]);
        }
        if (kt + 1 < NT) {
            __builtin_amdgcn_sched_barrier(0);
            __builtin_amdgcn_s_barrier();
            if (kt + 2 < NT) {
                stage(kt + 2, cur);
                asm volatile("s_waitcnt vmcnt(4)" ::: "memory");
            } else {
                asm volatile("s_waitcnt vmcnt(0)" ::: "memory");
            }
            __builtin_amdgcn_s_barrier();
        }
    }

#pragma unroll
    for (int m = 0; m < 4; ++m) {
#pragma unroll
        for (int j = 0; j < 4; ++j) {
            const int row = rowA0 + wm * 64 + m * 16 + hi * 4 + j;
#pragma unroll
            for (int n = 0; n < 2; ++n) {
                const int col = rowB0 + wn * 32 + n * 16 + lr;
                outp[(size_t)row * ldo + col] = acc[m][n][j];
            }
        }
    }
}

// out = p0(out) + p1 + bias + resid
__global__ __launch_bounds__(256) void reduce_fc2(
    float* __restrict__ outp, const float* __restrict__ p1,
    const float* __restrict__ bias, const float* __restrict__ resid) {
    const int i = blockIdx.x * 256 + threadIdx.x;
    const float4 a = ((const float4*)outp)[i];
    const float4 b = ((const float4*)p1)[i];
    const float4 r = ((const float4*)resid)[i];
    const float4 bv = ((const float4*)bias)[i & 255];
    float4 o;
    o.x = a.x + b.x + r.x + bv.x;
    o.y = a.y + b.y + r.y + bv.y;
    o.z = a.z + b.z + r.z + bv.z;
    o.w = a.w + b.w + r.w + bv.w;
    ((float4*)outp)[i] = o;
}

// ---------------- fused MLP GEMM: out = gelu(A@W1^T+b1) * sigmoid(A@Wg^T+bg)
__global__ __launch_bounds__(512, 4) void gemm_mlp(
    const bf16_t* __restrict__ A, int lda, const bf16_t* __restrict__ W1,
    const bf16_t* __restrict__ Wg, int ldw, const float* __restrict__ b1,
    const float* __restrict__ bg, bf16_t* __restrict__ outv, int ldo, int K,
    int nM) {
    __shared__ bf16_t As[2][8192];
    __shared__ bf16_t Bs[2][8192];
    const int tid = threadIdx.x;
    const int wave = tid >> 6, lane = tid & 63;
    const int wm = wave >> 2, wn = wave & 3;
    const int lr = lane & 15, hi = lane >> 4;

    const int x = blockIdx.x & 7, i = blockIdx.x >> 3;
    const int nc = (gridDim.x / nM) >> 3;
    const int nt = x * nc + (i % nc), mt = i / nc;
    const int rowA0 = mt * 128, colB0 = nt * 64;

    f32x4 acc[4][2];
#pragma unroll
    for (int m = 0; m < 4; ++m)
#pragma unroll
        for (int n = 0; n < 2; ++n) acc[m][n] = (f32x4){0.f, 0.f, 0.f, 0.f};

    const bf16_t* Wsrc = (wave & 1) ? Wg : W1;
    const int wrow = colB0 + (wave >> 1) * 16 + lr;
    auto stage = [&](int kt, int b) {
        const int k0 = kt * 64;
#pragma unroll
        for (int u = 0; u < 2; ++u) {
            const int c = wave * 2 + u;
            const int gcol = k0 + u * 32 + hi * 8;
            gload16(A + (size_t)(rowA0 + wave * 16 + lr) * lda + gcol,
                    &As[b][c * 512]);
            gload16(Wsrc + (size_t)wrow * ldw + gcol, &Bs[b][c * 512]);
        }
    };

    const int NT = K >> 6;
    stage(0, 0);
    stage(1, 1);
    asm volatile("s_waitcnt vmcnt(4)" ::: "memory");
    __builtin_amdgcn_s_barrier();

    for (int kt = 0; kt < NT; ++kt) {
        const int cur = kt & 1;
#pragma unroll
        for (int ks = 0; ks < 2; ++ks) {
            bf16x8 af[4], bh, bg_;
#pragma unroll
            for (int mf = 0; mf < 4; ++mf)
                af[mf] = *(const bf16x8*)&As[cur][((wm * 4 + mf) * 2 + ks) * 512 +
                                                 hi * 128 + lr * 8];
            bh = *(const bf16x8*)&Bs[cur][((2 * wn) * 2 + ks) * 512 + hi * 128 + lr * 8];
            bg_ = *(const bf16x8*)&Bs[cur][((2 * wn + 1) * 2 + ks) * 512 + hi * 128 + lr * 8];
#pragma unroll
            for (int mf = 0; mf < 4; ++mf) {
                acc[mf][0] = mfma16(af[mf], bh, acc[mf][0]);
                acc[mf][1] = mfma16(af[mf], bg_, acc[mf][1]);
            }
        }
        if (kt + 1 < NT) {
            __builtin_amdgcn_sched_barrier(0);
            __builtin_amdgcn_s_barrier();
            if (kt + 2 < NT) {
                stage(kt + 2, cur);
                asm volatile("s_waitcnt vmcnt(4)" ::: "memory");
            } else {
                asm volatile("s_waitcnt vmcnt(0)" ::: "memory");
            }
            __builtin_amdgcn_s_barrier();
        }
    }

    const int col = colB0 + wn * 16 + lr;
    const float bb1 = b1[col], bbg = bg[col];
#pragma unroll
    for (int m = 0; m < 4; ++m) {
#pragma unroll
        for (int j = 0; j < 4; ++j) {
            const int row = rowA0 + wm * 64 + m * 16 + hi * 4 + j;
            const float h = acc[m][0][j] + bb1;
            const float g = acc[m][1][j] + bbg;
            const float sg = 1.0f / (1.0f + __expf(-g));
            outv[(size_t)row * ldo + col] = (bf16_t)(epi_apply_gelu(h) * sg);
        }
    }
}

extern "C" void kernel_launch(void* const* d_in, const int* in_sizes, int n_in,
                              void* d_out, int out_size, void* d_ws, size_t ws_size,
                              hipStream_t stream) {
    const float* x = (const float*)d_in[0];
    const float* text_emb = (const float*)d_in[1];
    const float* rotary = (const float*)d_in[3];
    const float* ln1_g = (const float*)d_in[4];
    const float* ln1_b = (const float*)d_in[5];
    const float* ln2_g = (const float*)d_in[6];
    const float* ln2_b = (const float*)d_in[7];
    const float* ln3_g = (const float*)d_in[8];
    const float* ln3_b = (const float*)d_in[9];
    const float* attn_in_w = (const float*)d_in[10];
    const float* attn_in_b = (const float*)d_in[11];
    const float* ca_in_w = (const float*)d_in[12];
    const float* ca_in_b = (const float*)d_in[13];
    const float* ca_out_w = (const float*)d_in[14];
    const float* ca_out_b = (const float*)d_in[15];
    const float* fc1_w = (const float*)d_in[16];
    const float* fc1_b = (const float*)d_in[17];
    const float* gate_w = (const float*)d_in[18];
    const float* gate_b = (const float*)d_in[19];
    const float* fc2_w = (const float*)d_in[20];
    const float* fc2_b = (const float*)d_in[21];

    char* ws = (char*)d_ws;
    bf16_t* attn_w_bf = (bf16_t*)(ws);
    bf16_t* ca_in_bf = (bf16_t*)(ws + 6291456);
    bf16_t* ca_out_bf = (bf16_t*)(ws + 12582912);
    bf16_t* fc1_bf = (bf16_t*)(ws + 14680064);
    bf16_t* gate_bf = (bf16_t*)(ws + 23068672);
    bf16_t* fc2_bf = (bf16_t*)(ws + 31457280);
    bf16_t* text_bf = (bf16_t*)(ws + 39845888);
    bf16_t* xn = (bf16_t*)(ws + 41943040);
    float* xA = (float*)(ws + 50331648);
    float* fc2_p1 = (float*)(ws + 14680064);
    char* S = ws + 67108864;
    bf16_t* qkv = (bf16_t*)S;
    bf16_t* vtSelf = (bf16_t*)(S + 25165824);
    bf16_t* cq = (bf16_t*)S;
    bf16_t* ckv = (bf16_t*)(S + 8388608);
    bf16_t* ca_attn = (bf16_t*)(S + 12582912);
    bf16_t* vtCross = (bf16_t*)(S + 20971520);
    bf16_t* hbuf = (bf16_t*)S;
    float* out = (float*)d_out;

    cvt_all<<<20480, 256, 0, stream>>>(attn_in_w, attn_w_bf, ca_in_w, ca_in_bf,
                                       ca_out_w, ca_out_bf, fc1_w, fc1_bf,
                                       gate_w, gate_bf, fc2_w, fc2_bf,
                                       text_emb, text_bf);

    // ---- self-attention branch ----
    ln_kernel<<<4096, 256, 0, stream>>>(x, ln1_g, ln1_b, xn);
    gemm8w<EPI_BF16, 0><<<768, 512, 0, stream>>>(
        xn, 1024, attn_w_bf, 1024, attn_in_b, nullptr, qkv, 3072, 1024, 32);
    rope_kernel<<<8192, 256, 0, stream>>>(qkv, rotary);
    vtrans_kernel<<<dim3(16, 16, 4), 256, 0, stream>>>(qkv, 3072, 2048, 1024, vtSelf);
    attn3_kernel<false><<<512, 512, 0, stream>>>(
        qkv, 3072, 0, qkv, 3072, 1024, vtSelf, 1024, x, xA, 0.125f);

    // ---- cross-attention branch ----
    ln_kernel<<<4096, 256, 0, stream>>>(xA, ln2_g, ln2_b, xn);
    gemm8w<EPI_BF16, 0><<<256, 512, 0, stream>>>(
        xn, 1024, ca_in_bf, 1024, ca_in_b, nullptr, cq, 1024, 1024, 32);
    gemm8w<EPI_BF16, 1><<<128, 512, 0, stream>>>(
        text_bf, 1024, ca_in_bf + (size_t)1024 * 1024, 1024, ca_in_b + 1024, nullptr,
        ckv, 2048, 1024, 8);
    vtrans_kernel<<<dim3(4, 16, 4), 256, 0, stream>>>(ckv, 2048, 1024, 256, vtCross);
    attn3_kernel<true><<<512, 512, 0, stream>>>(
        cq, 1024, 0, ckv, 2048, 0, vtCross, 256, nullptr, ca_attn, 0.125f);
    gemm8w<EPI_F32_RESID, 0><<<256, 512, 0, stream>>>(
        ca_attn, 1024, ca_out_bf, 1024, ca_out_b, xA, xA, 1024, 1024, 32);

    // ---- MLP branch ----
    ln_kernel<<<4096, 256, 0, stream>>>(xA, ln3_g, ln3_b, xn);
    gemm_mlp<<<2048, 512, 0, stream>>>(
        xn, 1024, fc1_bf, gate_bf, 1024, fc1_b, gate_b, hbuf, 4096, 1024, 32);
    gemm8w_sk<<<512, 512, 0, stream>>>(
        hbuf, 4096, fc2_bf, 4096, out, fc2_p1, 1024, 2048, 32);
    reduce_fc2<<<4096, 256, 0, stream>>>(out, fc2_p1, fc2_b, xA);
}

// Round 21
// 474.102 us; speedup vs baseline: 1.0948x; 1.0075x over previous
//
#include <hip/hip_runtime.h>
#include <hip/hip_bf16.h>

#define SEQ 1024
#define DIM 1024
#define NH 16

typedef __bf16 bf16_t;
typedef __bf16 bf16x8 __attribute__((ext_vector_type(8)));
typedef __bf16 bf16x4 __attribute__((ext_vector_type(4)));
typedef float f32x4 __attribute__((ext_vector_type(4)));

__device__ __forceinline__ f32x4 mfma16(bf16x8 a, bf16x8 b, f32x4 c) {
    return __builtin_amdgcn_mfma_f32_16x16x32_bf16(a, b, c, 0, 0, 0);
}

__device__ __forceinline__ void gload16(const bf16_t* g, bf16_t* l) {
    __builtin_amdgcn_global_load_lds(
        (const __attribute__((address_space(1))) void*)g,
        (__attribute__((address_space(3))) void*)l, 16, 0, 0);
}

enum { EPI_BF16 = 0, EPI_F32_RESID = 1 };

// ---------------- fused f32 -> bf16 conversion (all weights + text) ---------
__global__ __launch_bounds__(256) void cvt_all(
    const float* __restrict__ s0, bf16_t* __restrict__ d0,
    const float* __restrict__ s1, bf16_t* __restrict__ d1,
    const float* __restrict__ s2, bf16_t* __restrict__ d2,
    const float* __restrict__ s3, bf16_t* __restrict__ d3,
    const float* __restrict__ s4, bf16_t* __restrict__ d4,
    const float* __restrict__ s5, bf16_t* __restrict__ d5,
    const float* __restrict__ s6, bf16_t* __restrict__ d6) {
    const int b = blockIdx.x;
    const float* s;
    bf16_t* d;
    int off;
    if (b < 3072) { s = s0; d = d0; off = b; }
    else if (b < 6144) { s = s1; d = d1; off = b - 3072; }
    else if (b < 7168) { s = s2; d = d2; off = b - 6144; }
    else if (b < 11264) { s = s3; d = d3; off = b - 7168; }
    else if (b < 15360) { s = s4; d = d4; off = b - 11264; }
    else if (b < 19456) { s = s5; d = d5; off = b - 15360; }
    else { s = s6; d = d6; off = b - 19456; }
    const int i = off * 256 + threadIdx.x;
    const float4 v = ((const float4*)s)[i];
    bf16x4 o = {(bf16_t)v.x, (bf16_t)v.y, (bf16_t)v.z, (bf16_t)v.w};
    ((bf16x4*)d)[i] = o;
}

// ---------------- LayerNorm ---------------------------------------------------
__global__ __launch_bounds__(256) void ln_kernel(const float* __restrict__ in,
                                                 const float* __restrict__ g,
                                                 const float* __restrict__ bsh,
                                                 bf16_t* __restrict__ out) {
    __shared__ float red[4], red2[4];
    const int row = blockIdx.x, tid = threadIdx.x;
    const float4 v = ((const float4*)(in + (size_t)row * DIM))[tid];
    float s = v.x + v.y + v.z + v.w;
#pragma unroll
    for (int o = 32; o; o >>= 1) s += __shfl_down(s, o, 64);
    if ((tid & 63) == 0) red[tid >> 6] = s;
    __syncthreads();
    const float mean = (red[0] + red[1] + red[2] + red[3]) * (1.0f / DIM);
    const float dx = v.x - mean, dy = v.y - mean, dz = v.z - mean, dw = v.w - mean;
    float s2 = dx * dx + dy * dy + dz * dz + dw * dw;
#pragma unroll
    for (int o = 32; o; o >>= 1) s2 += __shfl_xor(s2, o, 64);
    if ((tid & 63) == 0) red2[tid >> 6] = s2;
    __syncthreads();
    const float var = (red2[0] + red2[1] + red2[2] + red2[3]) * (1.0f / DIM);
    const float rs = rsqrtf(var + 1e-5f);
    const float4 gv = ((const float4*)g)[tid];
    const float4 bv = ((const float4*)bsh)[tid];
    bf16x4 o4 = {(bf16_t)(dx * rs * gv.x + bv.x), (bf16_t)(dy * rs * gv.y + bv.y),
                 (bf16_t)(dz * rs * gv.z + bv.z), (bf16_t)(dw * rs * gv.w + bv.w)};
    ((bf16x4*)(out + (size_t)row * DIM))[tid] = o4;
}

// ---------------- RoPE -------------------------------------------------------
__global__ __launch_bounds__(256) void rope_kernel(bf16_t* __restrict__ qkv,
                                                   const float* __restrict__ rp) {
    const int t = blockIdx.x * 256 + threadIdx.x;
    const int row = t >> 9;
    const int rem = t & 511;
    const int h = rem >> 5, d = rem & 31;
    const int s = row & (SEQ - 1);
    const float p0 = rp[s * 64 + d];
    const float p1 = rp[s * 64 + d + 32];
    float s0, c0, s1, c1;
    sincosf(p0, &s0, &c0);
    sincosf(p1, &s1, &c1);
    const size_t base = (size_t)row * 3072 + h * 64 + d;
#pragma unroll
    for (int off = 0; off <= 1024; off += 1024) {
        const float a = (float)qkv[base + off];
        const float b = (float)qkv[base + off + 32];
        qkv[base + off] = (bf16_t)(a * c0 - b * s0);
        qkv[base + off + 32] = (bf16_t)(b * c1 + a * s1);
    }
}

__device__ __forceinline__ float epi_apply_gelu(float v) {
    return 0.5f * v * (1.0f + erff(v * 0.70710678118f));
}

// ---------------- V^T precompute ---------------------------------------------
__global__ __launch_bounds__(256) void vtrans_kernel(
    const bf16_t* __restrict__ src, int ld, int voff, int skv,
    bf16_t* __restrict__ vt) {
    __shared__ bf16_t T[64 * 72];
    const int qt = blockIdx.x, h = blockIdx.y, b = blockIdx.z;
    const int tid = threadIdx.x;
    const int s0 = qt * 64;
#pragma unroll
    for (int t = 0; t < 2; ++t) {
        const int idx = t * 256 + tid;
        const int r = idx >> 3, c8 = (idx & 7) * 8;
        bf16x8 v = *(const bf16x8*)(src + (size_t)(b * skv + s0 + r) * ld +
                                    voff + h * 64 + c8);
        *(bf16x8*)&T[r * 72 + c8] = v;
    }
    __syncthreads();
    const size_t base = ((size_t)(b * NH + h) * 64) * skv;
#pragma unroll
    for (int t = 0; t < 2; ++t) {
        const int idx = t * 256 + tid;
        const int d = idx >> 3, s8 = (idx & 7) * 8;
        bf16x8 w;
#pragma unroll
        for (int i = 0; i < 8; ++i) w[i] = T[(s8 + i) * 72 + d];
        *(bf16x8*)(vt + base + (size_t)d * skv + s0 + s8) = w;
    }
}

// ---------------- flash attention v3: 8 waves, 128 q-rows/block -------------
#define ALD 72
template <bool OUTBF>
__global__ __launch_bounds__(512) void attn3_kernel(
    const bf16_t* __restrict__ qp, int ldq, int qoff,
    const bf16_t* __restrict__ kp, int ldk, int koff,
    const bf16_t* __restrict__ vtp, int skv,
    const float* __restrict__ resid, void* __restrict__ outp, float scale) {
    __shared__ bf16_t Ks[4096];
    __shared__ bf16_t Vs[4096];
    __shared__ bf16_t Ps[8 * 16 * ALD];
    const int nwg = gridDim.x;
    const int t = (blockIdx.x & 7) * (nwg >> 3) + (blockIdx.x >> 3);
    const int qt = t & 7;
    const int bh = t >> 3;
    const int b = bh >> 4, h = bh & 15;
    const int tid = threadIdx.x;
    const int wave = tid >> 6, lane = tid & 63;
    const int lr = lane & 15, hi = lane >> 4;

    const size_t qrow = (size_t)(b * SEQ + qt * 128 + wave * 16 + lr);
    const bf16_t* qb = qp + qrow * ldq + qoff + h * 64;
    const bf16x8 qf0 = *(const bf16x8*)(qb + hi * 8);
    const bf16x8 qf1 = *(const bf16x8*)(qb + 32 + hi * 8);

    const bf16_t* vbase = vtp + ((size_t)bh * 64) * skv;

    f32x4 oacc[4];
#pragma unroll
    for (int n = 0; n < 4; ++n) oacc[n] = (f32x4){0.f, 0.f, 0.f, 0.f};
    float mrun[4] = {-1e30f, -1e30f, -1e30f, -1e30f};
    float lrun[4] = {0.f, 0.f, 0.f, 0.f};

    bf16_t* pw = &Ps[wave * 16 * ALD];
    const int nkt = skv >> 6;
    for (int kt = 0; kt < nkt; ++kt) {
        {
            const int grow = (wave >> 1) * 16 + lr, gcol = (wave & 1) * 32 + hi * 8;
            gload16(kp + (size_t)(b * skv + kt * 64 + grow) * ldk + koff +
                        h * 64 + gcol,
                    &Ks[wave * 512]);
            gload16(vbase + (size_t)grow * skv + kt * 64 + gcol, &Vs[wave * 512]);
        }
        __syncthreads();

        f32x4 s[4];
#pragma unroll
        for (int n = 0; n < 4; ++n) {
            f32x4 z = (f32x4){0.f, 0.f, 0.f, 0.f};
            z = mfma16(qf0, *(const bf16x8*)&Ks[(n * 2 + 0) * 512 + lane * 8], z);
            z = mfma16(qf1, *(const bf16x8*)&Ks[(n * 2 + 1) * 512 + lane * 8], z);
            s[n] = z * scale;
        }
        float alpha[4];
#pragma unroll
        for (int j = 0; j < 4; ++j) {
            float mt = fmaxf(fmaxf(s[0][j], s[1][j]), fmaxf(s[2][j], s[3][j]));
#pragma unroll
            for (int o = 8; o >= 1; o >>= 1) mt = fmaxf(mt, __shfl_xor(mt, o, 64));
            const float mnew = fmaxf(mrun[j], mt);
            alpha[j] = __expf(mrun[j] - mnew);
            float rsum = 0.f;
#pragma unroll
            for (int n = 0; n < 4; ++n) {
                const float p = __expf(s[n][j] - mnew);
                s[n][j] = p;
                rsum += p;
            }
#pragma unroll
            for (int o = 8; o >= 1; o >>= 1) rsum += __shfl_xor(rsum, o, 64);
            lrun[j] = lrun[j] * alpha[j] + rsum;
            mrun[j] = mnew;
        }
#pragma unroll
        for (int j = 0; j < 4; ++j) {
            const int pr = hi * 4 + j;
#pragma unroll
            for (int n = 0; n < 4; ++n) pw[pr * ALD + n * 16 + lr] = (bf16_t)s[n][j];
        }
#pragma unroll
        for (int n = 0; n < 4; ++n)
#pragma unroll
            for (int j = 0; j < 4; ++j) oacc[n][j] *= alpha[j];
#pragma unroll
        for (int ks = 0; ks < 2; ++ks) {
            const bf16x8 pa = *(const bf16x8*)&pw[lr * ALD + ks * 32 + hi * 8];
#pragma unroll
            for (int n = 0; n < 4; ++n) {
                const bf16x8 vf =
                    *(const bf16x8*)&Vs[(n * 2 + ks) * 512 + lane * 8];
                oacc[n] = mfma16(pa, vf, oacc[n]);
            }
        }
        __syncthreads();
    }

    const size_t orow0 = (size_t)(b * SEQ + qt * 128 + wave * 16);
#pragma unroll
    for (int n = 0; n < 4; ++n) {
#pragma unroll
        for (int j = 0; j < 4; ++j) {
            const int r = hi * 4 + j;
            const size_t idx = (orow0 + r) * DIM + h * 64 + n * 16 + lr;
            float val = oacc[n][j] / lrun[j];
            if constexpr (OUTBF) {
                ((bf16_t*)outp)[idx] = (bf16_t)val;
            } else {
                ((float*)outp)[idx] = val + resid[idx];
            }
        }
    }
}

// ---------------- 128x128 bf16 GEMM, 8 waves, BK=32, 32KB LDS ---------------
// 4 blocks/CU -> 8 waves/SIMD (hardware max). Per K-tile each wave stages 1
// A-chunk + 1 B-chunk (chunk c=wave: rows c*16..+15, 32 cols; lane l holds
// row c*16+(l&15), cols (l>>4)*8 at elem c*512+l*8 — staging linear,
// fragment reads identity). Dist-2 counted pipeline, vmcnt(2).
template <int EPI, int MODE>
__global__ __launch_bounds__(512, 8) void gemm8w32(
    const bf16_t* __restrict__ A, int lda, const bf16_t* __restrict__ W, int ldw,
    const float* __restrict__ bias, const void* __restrict__ aux,
    void* __restrict__ outv, int ldo, int K, int nM) {
    __shared__ bf16_t As[2][4096];
    __shared__ bf16_t Bs[2][4096];
    const int tid = threadIdx.x;
    const int wave = tid >> 6, lane = tid & 63;
    const int wm = wave >> 2, wn = wave & 3;
    const int lr = lane & 15, hi = lane >> 4;

    const int x = blockIdx.x & 7, i = blockIdx.x >> 3;
    int mt, nt;
    if constexpr (MODE == 0) {
        const int mc = nM >> 3;
        mt = x * mc + (i % mc);
        nt = i / mc;
    } else {
        const int nc = (gridDim.x / nM) >> 3;
        nt = x * nc + (i % nc);
        mt = i / nc;
    }
    const int rowA0 = mt * 128, rowB0 = nt * 128;

    f32x4 acc[4][2];
#pragma unroll
    for (int m = 0; m < 4; ++m)
#pragma unroll
        for (int n = 0; n < 2; ++n) acc[m][n] = (f32x4){0.f, 0.f, 0.f, 0.f};

    auto stage = [&](int kt, int b) {
        const int gcol = kt * 32 + hi * 8;
        const int grow = wave * 16 + lr;
        gload16(A + (size_t)(rowA0 + grow) * lda + gcol, &As[b][wave * 512]);
        gload16(W + (size_t)(rowB0 + grow) * ldw + gcol, &Bs[b][wave * 512]);
    };

    const int NT = K >> 5;
    stage(0, 0);
    stage(1, 1);
    asm volatile("s_waitcnt vmcnt(2)" ::: "memory");
    __builtin_amdgcn_s_barrier();

    for (int kt = 0; kt < NT; ++kt) {
        const int cur = kt & 1;
        bf16x8 af[4], bfr[2];
#pragma unroll
        for (int mf = 0; mf < 4; ++mf)
            af[mf] = *(const bf16x8*)&As[cur][(wm * 4 + mf) * 512 + lane * 8];
#pragma unroll
        for (int nf = 0; nf < 2; ++nf)
            bfr[nf] = *(const bf16x8*)&Bs[cur][(wn * 2 + nf) * 512 + lane * 8];
#pragma unroll
        for (int mf = 0; mf < 4; ++mf)
#pragma unroll
            for (int nf = 0; nf < 2; ++nf)
                acc[mf][nf] = mfma16(af[mf], bfr[nf], acc[mf][nf]);
        if (kt + 1 < NT) {
            __builtin_amdgcn_sched_barrier(0);
            __builtin_amdgcn_s_barrier();
            if (kt + 2 < NT) {
                stage(kt + 2, cur);
                asm volatile("s_waitcnt vmcnt(2)" ::: "memory");
            } else {
                asm volatile("s_waitcnt vmcnt(0)" ::: "memory");
            }
            __builtin_amdgcn_s_barrier();
        }
    }

    float bn[2];
#pragma unroll
    for (int n = 0; n < 2; ++n) bn[n] = bias[rowB0 + wn * 32 + n * 16 + lr];
#pragma unroll
    for (int m = 0; m < 4; ++m) {
#pragma unroll
        for (int j = 0; j < 4; ++j) {
            const int row = rowA0 + wm * 64 + m * 16 + hi * 4 + j;
#pragma unroll
            for (int n = 0; n < 2; ++n) {
                const int col = rowB0 + wn * 32 + n * 16 + lr;
                float val = acc[m][n][j] + bn[n];
                const size_t oidx = (size_t)row * ldo + col;
                if constexpr (EPI == EPI_BF16) {
                    ((bf16_t*)outv)[oidx] = (bf16_t)val;
                } else {
                    ((float*)outv)[oidx] = val + ((const float*)aux)[oidx];
                }
            }
        }
    }
}

// ---------------- split-K fc2 GEMM, BK=32 version ---------------------------
__global__ __launch_bounds__(512, 8) void gemm_sk32(
    const bf16_t* __restrict__ A, int lda, const bf16_t* __restrict__ W, int ldw,
    float* __restrict__ p0, float* __restrict__ p1, int ldo, int Khalf, int nM) {
    __shared__ bf16_t As[2][4096];
    __shared__ bf16_t Bs[2][4096];
    const int tid = threadIdx.x;
    const int wave = tid >> 6, lane = tid & 63;
    const int wm = wave >> 2, wn = wave & 3;
    const int lr = lane & 15, hi = lane >> 4;

    const int sk = blockIdx.x >> 8;
    const int bi = blockIdx.x & 255;
    const int x = bi & 7, i = bi >> 3;
    const int mc = nM >> 3;
    const int mt = x * mc + (i % mc);
    const int nt = i / mc;
    const int rowA0 = mt * 128, rowB0 = nt * 128;
    const int kbase = sk * Khalf;
    float* outp = sk ? p1 : p0;

    f32x4 acc[4][2];
#pragma unroll
    for (int m = 0; m < 4; ++m)
#pragma unroll
        for (int n = 0; n < 2; ++n) acc[m][n] = (f32x4){0.f, 0.f, 0.f, 0.f};

    auto stage = [&](int kt, int b) {
        const int gcol = kbase + kt * 32 + hi * 8;
        const int grow = wave * 16 + lr;
        gload16(A + (size_t)(rowA0 + grow) * lda + gcol, &As[b][wave * 512]);
        gload16(W + (size_t)(rowB0 + grow) * ldw + gcol, &Bs[b][wave * 512]);
    };

    const int NT = Khalf >> 5;
    stage(0, 0);
    stage(1, 1);
    asm volatile("s_waitcnt vmcnt(2)" ::: "memory");
    __builtin_amdgcn_s_barrier();

    for (int kt = 0; kt < NT; ++kt) {
        const int cur = kt & 1;
        bf16x8 af[4], bfr[2];
#pragma unroll
        for (int mf = 0; mf < 4; ++mf)
            af[mf] = *(const bf16x8*)&As[cur][(wm * 4 + mf) * 512 + lane * 8];
#pragma unroll
        for (int nf = 0; nf < 2; ++nf)
            bfr[nf] = *(const bf16x8*)&Bs[cur][(wn * 2 + nf) * 512 + lane * 8];
#pragma unroll
        for (int mf = 0; mf < 4; ++mf)
#pragma unroll
            for (int nf = 0; nf < 2; ++nf)
                acc[mf][nf] = mfma16(af[mf], bfr[nf], acc[mf][nf]);
        if (kt + 1 < NT) {
            __builtin_amdgcn_sched_barrier(0);
            __builtin_amdgcn_s_barrier();
            if (kt + 2 < NT) {
                stage(kt + 2, cur);
                asm volatile("s_waitcnt vmcnt(2)" ::: "memory");
            } else {
                asm volatile("s_waitcnt vmcnt(0)" ::: "memory");
            }
            __builtin_amdgcn_s_barrier();
        }
    }

#pragma unroll
    for (int m = 0; m < 4; ++m) {
#pragma unroll
        for (int j = 0; j < 4; ++j) {
            const int row = rowA0 + wm * 64 + m * 16 + hi * 4 + j;
#pragma unroll
            for (int n = 0; n < 2; ++n) {
                const int col = rowB0 + wn * 32 + n * 16 + lr;
                outp[(size_t)row * ldo + col] = acc[m][n][j];
            }
        }
    }
}

// out = p0(out) + p1 + bias + resid
__global__ __launch_bounds__(256) void reduce_fc2(
    float* __restrict__ outp, const float* __restrict__ p1,
    const float* __restrict__ bias, const float* __restrict__ resid) {
    const int i = blockIdx.x * 256 + threadIdx.x;
    const float4 a = ((const float4*)outp)[i];
    const float4 b = ((const float4*)p1)[i];
    const float4 r = ((const float4*)resid)[i];
    const float4 bv = ((const float4*)bias)[i & 255];
    float4 o;
    o.x = a.x + b.x + r.x + bv.x;
    o.y = a.y + b.y + r.y + bv.y;
    o.z = a.z + b.z + r.z + bv.z;
    o.w = a.w + b.w + r.w + bv.w;
    ((float4*)outp)[i] = o;
}

// ---------------- fused MLP GEMM, BK=32: gelu(A@W1^T+b1)*sigmoid(A@Wg^T+bg) -
// B-tile = 8 chunks: c<4 -> W1 rows colB0+(c&3)*16, c>=4 -> Wg rows
// colB0+(c&3)*16 (layout validated in round 14's gemm_mlp_d).
__global__ __launch_bounds__(512, 8) void gemm_mlp32(
    const bf16_t* __restrict__ A, int lda, const bf16_t* __restrict__ W1,
    const bf16_t* __restrict__ Wg, int ldw, const float* __restrict__ b1,
    const float* __restrict__ bg, bf16_t* __restrict__ outv, int ldo, int K,
    int nM) {
    __shared__ bf16_t As[2][4096];
    __shared__ bf16_t Bs[2][4096];
    const int tid = threadIdx.x;
    const int wave = tid >> 6, lane = tid & 63;
    const int wm = wave >> 2, wn = wave & 3;
    const int lr = lane & 15, hi = lane >> 4;

    const int x = blockIdx.x & 7, i = blockIdx.x >> 3;
    const int nc = (gridDim.x / nM) >> 3;
    const int nt = x * nc + (i % nc), mt = i / nc;
    const int rowA0 = mt * 128, colB0 = nt * 64;

    f32x4 acc[4][2];  // [m][0]=h, [m][1]=g
#pragma unroll
    for (int m = 0; m < 4; ++m)
#pragma unroll
        for (int n = 0; n < 2; ++n) acc[m][n] = (f32x4){0.f, 0.f, 0.f, 0.f};

    const bf16_t* Wsrc = (wave < 4) ? W1 : Wg;
    const int wrow = colB0 + (wave & 3) * 16 + lr;
    auto stage = [&](int kt, int b) {
        const int gcol = kt * 32 + hi * 8;
        gload16(A + (size_t)(rowA0 + wave * 16 + lr) * lda + gcol,
                &As[b][wave * 512]);
        gload16(Wsrc + (size_t)wrow * ldw + gcol, &Bs[b][wave * 512]);
    };

    const int NT = K >> 5;
    stage(0, 0);
    stage(1, 1);
    asm volatile("s_waitcnt vmcnt(2)" ::: "memory");
    __builtin_amdgcn_s_barrier();

    for (int kt = 0; kt < NT; ++kt) {
        const int cur = kt & 1;
        bf16x8 af[4], bh, bg_;
#pragma unroll
        for (int mf = 0; mf < 4; ++mf)
            af[mf] = *(const bf16x8*)&As[cur][(wm * 4 + mf) * 512 + lane * 8];
        bh = *(const bf16x8*)&Bs[cur][wn * 512 + lane * 8];
        bg_ = *(const bf16x8*)&Bs[cur][(4 + wn) * 512 + lane * 8];
#pragma unroll
        for (int mf = 0; mf < 4; ++mf) {
            acc[mf][0] = mfma16(af[mf], bh, acc[mf][0]);
            acc[mf][1] = mfma16(af[mf], bg_, acc[mf][1]);
        }
        if (kt + 1 < NT) {
            __builtin_amdgcn_sched_barrier(0);
            __builtin_amdgcn_s_barrier();
            if (kt + 2 < NT) {
                stage(kt + 2, cur);
                asm volatile("s_waitcnt vmcnt(2)" ::: "memory");
            } else {
                asm volatile("s_waitcnt vmcnt(0)" ::: "memory");
            }
            __builtin_amdgcn_s_barrier();
        }
    }

    const int col = colB0 + wn * 16 + lr;
    const float bb1 = b1[col], bbg = bg[col];
#pragma unroll
    for (int m = 0; m < 4; ++m) {
#pragma unroll
        for (int j = 0; j < 4; ++j) {
            const int row = rowA0 + wm * 64 + m * 16 + hi * 4 + j;
            const float h = acc[m][0][j] + bb1;
            const float g = acc[m][1][j] + bbg;
            const float sg = 1.0f / (1.0f + __expf(-g));
            outv[(size_t)row * ldo + col] = (bf16_t)(epi_apply_gelu(h) * sg);
        }
    }
}

extern "C" void kernel_launch(void* const* d_in, const int* in_sizes, int n_in,
                              void* d_out, int out_size, void* d_ws, size_t ws_size,
                              hipStream_t stream) {
    const float* x = (const float*)d_in[0];
    const float* text_emb = (const float*)d_in[1];
    const float* rotary = (const float*)d_in[3];
    const float* ln1_g = (const float*)d_in[4];
    const float* ln1_b = (const float*)d_in[5];
    const float* ln2_g = (const float*)d_in[6];
    const float* ln2_b = (const float*)d_in[7];
    const float* ln3_g = (const float*)d_in[8];
    const float* ln3_b = (const float*)d_in[9];
    const float* attn_in_w = (const float*)d_in[10];
    const float* attn_in_b = (const float*)d_in[11];
    const float* ca_in_w = (const float*)d_in[12];
    const float* ca_in_b = (const float*)d_in[13];
    const float* ca_out_w = (const float*)d_in[14];
    const float* ca_out_b = (const float*)d_in[15];
    const float* fc1_w = (const float*)d_in[16];
    const float* fc1_b = (const float*)d_in[17];
    const float* gate_w = (const float*)d_in[18];
    const float* gate_b = (const float*)d_in[19];
    const float* fc2_w = (const float*)d_in[20];
    const float* fc2_b = (const float*)d_in[21];

    char* ws = (char*)d_ws;
    bf16_t* attn_w_bf = (bf16_t*)(ws);
    bf16_t* ca_in_bf = (bf16_t*)(ws + 6291456);
    bf16_t* ca_out_bf = (bf16_t*)(ws + 12582912);
    bf16_t* fc1_bf = (bf16_t*)(ws + 14680064);
    bf16_t* gate_bf = (bf16_t*)(ws + 23068672);
    bf16_t* fc2_bf = (bf16_t*)(ws + 31457280);
    bf16_t* text_bf = (bf16_t*)(ws + 39845888);
    bf16_t* xn = (bf16_t*)(ws + 41943040);
    float* xA = (float*)(ws + 50331648);
    float* fc2_p1 = (float*)(ws + 14680064);
    char* S = ws + 67108864;
    bf16_t* qkv = (bf16_t*)S;
    bf16_t* vtSelf = (bf16_t*)(S + 25165824);
    bf16_t* cq = (bf16_t*)S;
    bf16_t* ckv = (bf16_t*)(S + 8388608);
    bf16_t* ca_attn = (bf16_t*)(S + 12582912);
    bf16_t* vtCross = (bf16_t*)(S + 20971520);
    bf16_t* hbuf = (bf16_t*)S;
    float* out = (float*)d_out;

    cvt_all<<<20480, 256, 0, stream>>>(attn_in_w, attn_w_bf, ca_in_w, ca_in_bf,
                                       ca_out_w, ca_out_bf, fc1_w, fc1_bf,
                                       gate_w, gate_bf, fc2_w, fc2_bf,
                                       text_emb, text_bf);

    // ---- self-attention branch ----
    ln_kernel<<<4096, 256, 0, stream>>>(x, ln1_g, ln1_b, xn);
    gemm8w32<EPI_BF16, 0><<<768, 512, 0, stream>>>(
        xn, 1024, attn_w_bf, 1024, attn_in_b, nullptr, qkv, 3072, 1024, 32);
    rope_kernel<<<8192, 256, 0, stream>>>(qkv, rotary);
    vtrans_kernel<<<dim3(16, 16, 4), 256, 0, stream>>>(qkv, 3072, 2048, 1024, vtSelf);
    attn3_kernel<false><<<512, 512, 0, stream>>>(
        qkv, 3072, 0, qkv, 3072, 1024, vtSelf, 1024, x, xA, 0.125f);

    // ---- cross-attention branch ----
    ln_kernel<<<4096, 256, 0, stream>>>(xA, ln2_g, ln2_b, xn);
    gemm8w32<EPI_BF16, 0><<<256, 512, 0, stream>>>(
        xn, 1024, ca_in_bf, 1024, ca_in_b, nullptr, cq, 1024, 1024, 32);
    gemm8w32<EPI_BF16, 1><<<128, 512, 0, stream>>>(
        text_bf, 1024, ca_in_bf + (size_t)1024 * 1024, 1024, ca_in_b + 1024, nullptr,
        ckv, 2048, 1024, 8);
    vtrans_kernel<<<dim3(4, 16, 4), 256, 0, stream>>>(ckv, 2048, 1024, 256, vtCross);
    attn3_kernel<true><<<512, 512, 0, stream>>>(
        cq, 1024, 0, ckv, 2048, 0, vtCross, 256, nullptr, ca_attn, 0.125f);
    gemm8w32<EPI_F32_RESID, 0><<<256, 512, 0, stream>>>(
        ca_attn, 1024, ca_out_bf, 1024, ca_out_b, xA, xA, 1024, 1024, 32);

    // ---- MLP branch ----
    ln_kernel<<<4096, 256, 0, stream>>>(xA, ln3_g, ln3_b, xn);
    gemm_mlp32<<<2048, 512, 0, stream>>>(
        xn, 1024, fc1_bf, gate_bf, 1024, fc1_b, gate_b, hbuf, 4096, 1024, 32);
    gemm_sk32<<<512, 512, 0, stream>>>(
        hbuf, 4096, fc2_bf, 4096, out, fc2_p1, 1024, 2048, 32);
    reduce_fc2<<<4096, 256, 0, stream>>>(out, fc2_p1, fc2_b, xA);
}